// Round 1
// baseline (77.051 us; speedup 1.0000x reference)
//
#include <hip/hip_runtime.h>
#include <math.h>

// Problem constants (from reference):
//   x: (64,1,128,128) f32, K=2 conv -> 127x127 patches per image
//   quantum: 4 qubits, but CNOTs only couple (0,1) and (2,3); Z0 readout
//   => q_out depends only on wires 0,1 = x[i,j], x[i,j+1].
//   The RY/CNOT ladder is a constant real 4x4 unitary U; with the RX product
//   state a = r + i*m  (r=(c0c1,0,0,-s0s1), m=(0,-c0s1,-s0c1,0)),
//   <Z0> = sum_k g_k[(U r)_k^2 + (U m)_k^2],  g=(+,+,-,-)
//   which reduces to: q = k0 + k1 cosT0 + k2 cosT1 + k3 cosT0 cosT1 + k4 sinT0 sinT1.

#define XH 128
#define XW 128
#define PH 127
#define PW 127
#define NP (PH * PW)   // 16129 patches per image
#define NB 64          // batch
#define BLK 512

__global__ __launch_bounds__(BLK) void convdual_kernel(
    const float* __restrict__ x,       // (64,1,128,128)
    const float* __restrict__ conv_w,  // 4
    const float* __restrict__ conv_b,  // 1
    const float* __restrict__ ry,      // (2,4)
    const float* __restrict__ head_w,  // 2
    const float* __restrict__ head_b,  // 1
    float* __restrict__ out)           // 64
{
    __shared__ float sc[5];            // k0..k4
    __shared__ float red[BLK / 64];    // per-wave partials

    const int b   = blockIdx.x;
    const int tid = threadIdx.x;

    // ---- one thread builds the circuit coefficients (uniform, ~100 flops) ----
    if (tid == 0) {
        float U[4][4];
        for (int i = 0; i < 4; ++i)
            for (int j = 0; j < 4; ++j)
                U[i][j] = (i == j) ? 1.f : 0.f;
        for (int l = 0; l < 2; ++l) {
            float c0 = cosf(0.5f * ry[l * 4 + 0]), s0 = sinf(0.5f * ry[l * 4 + 0]);
            float c1 = cosf(0.5f * ry[l * 4 + 1]), s1 = sinf(0.5f * ry[l * 4 + 1]);
            // RY on q0 (index k = 2*q0 + q1): rows (q1, 2+q1)
            for (int q1 = 0; q1 < 2; ++q1)
                for (int c = 0; c < 4; ++c) {
                    float a = U[q1][c], d = U[2 + q1][c];
                    U[q1][c]     = c0 * a - s0 * d;
                    U[2 + q1][c] = s0 * a + c0 * d;
                }
            // RY on q1: rows (2k, 2k+1)
            for (int k = 0; k < 2; ++k)
                for (int c = 0; c < 4; ++c) {
                    float a = U[2 * k][c], d = U[2 * k + 1][c];
                    U[2 * k][c]     = c1 * a - s1 * d;
                    U[2 * k + 1][c] = s1 * a + c1 * d;
                }
            // CNOT(ctrl=q0, tgt=q1): swap rows 2,3
            for (int c = 0; c < 4; ++c) {
                float t = U[2][c]; U[2][c] = U[3][c]; U[3][c] = t;
            }
        }
        float pA = 0, pB = 0, pC = 0, pD = 0, pAD = 0, pBC = 0;
        for (int k = 0; k < 4; ++k) {
            float g = (k < 2) ? 1.f : -1.f;
            pA  += g * U[k][0] * U[k][0];
            pB  += g * U[k][1] * U[k][1];
            pC  += g * U[k][2] * U[k][2];
            pD  += g * U[k][3] * U[k][3];
            pAD += g * U[k][0] * U[k][3];
            pBC += g * U[k][1] * U[k][2];
        }
        sc[0] = 0.25f * (pA + pB + pC + pD);
        sc[1] = 0.25f * (pA + pB - pC - pD);
        sc[2] = 0.25f * (pA - pB + pC - pD);
        sc[3] = 0.25f * (pA - pB - pC + pD);
        sc[4] = 0.50f * (pBC - pAD);
    }
    __syncthreads();

    const float w0 = conv_w[0], w1 = conv_w[1], w2 = conv_w[2], w3 = conv_w[3];
    const float hw0 = head_w[0], hw1 = head_w[1];
    const float k1 = sc[1], k2 = sc[2], k3 = sc[3], k4 = sc[4];
    // per-patch constant term folds into the mean directly
    const float cconst = hw0 * conv_b[0] + hw1 * sc[0] + head_b[0];

    const float* __restrict__ xb = x + (size_t)b * XH * XW;

    float acc = 0.f;
    for (int p = tid; p < NP; p += BLK) {
        int i = p / PW;
        int j = p - i * PW;
        float x00 = xb[i * XW + j];
        float x01 = xb[i * XW + j + 1];
        float x10 = xb[(i + 1) * XW + j];
        float x11 = xb[(i + 1) * XW + j + 1];
        float conv = w0 * x00 + w1 * x01 + w2 * x10 + w3 * x11;
        float s0, c0, s1, c1;
        __sincosf(x00, &s0, &c0);
        __sincosf(x01, &s1, &c1);
        float q = k1 * c0 + k2 * c1 + k3 * c0 * c1 + k4 * s0 * s1;
        acc += hw0 * conv + hw1 * q;
    }

    // ---- block reduction: wave shuffle, then cross-wave via LDS ----
    for (int off = 32; off > 0; off >>= 1)
        acc += __shfl_down(acc, off, 64);
    int wave = tid >> 6;
    if ((tid & 63) == 0) red[wave] = acc;
    __syncthreads();
    if (tid == 0) {
        float tot = 0.f;
        for (int w = 0; w < BLK / 64; ++w) tot += red[w];
        out[b] = tot * (1.0f / NP) + cconst;
    }
}

extern "C" void kernel_launch(void* const* d_in, const int* in_sizes, int n_in,
                              void* d_out, int out_size, void* d_ws, size_t ws_size,
                              hipStream_t stream) {
    const float* x      = (const float*)d_in[0];
    const float* conv_w = (const float*)d_in[1];
    const float* conv_b = (const float*)d_in[2];
    const float* ry     = (const float*)d_in[3];
    const float* head_w = (const float*)d_in[4];
    const float* head_b = (const float*)d_in[5];
    float* out = (float*)d_out;

    convdual_kernel<<<NB, BLK, 0, stream>>>(x, conv_w, conv_b, ry, head_w, head_b, out);
}

// Round 2
// 69.793 us; speedup vs baseline: 1.1040x; 1.1040x over previous
//
#include <hip/hip_runtime.h>
#include <math.h>

// x: (64,1,128,128) f32 -> K=2 conv -> 127x127 patches/image.
// Quantum circuit collapses analytically (CNOTs only couple (0,1),(2,3); Z0
// readout => wires 2,3 trace out):
//   q = k0 + k1*cos(t0) + k2*cos(t1) + k3*cos(t0)cos(t1) + k4*sin(t0)sin(t1)
// where t0=x[i,j], t1=x[i,j+1] and k0..k4 derive from the constant real 4x4
// RY/CNOT unitary U:  <Z0> = sum_k g_k[(U r)_k^2 + (U m)_k^2], g=(+,+,-,-).

#define XH 128
#define XW 128
#define PW 127
#define NP (127 * 127)   // 16129 patches per image
#define NB 64            // batch
#define SLICES 32        // blocks per image
#define PPB ((NP + SLICES - 1) / SLICES)  // 505 patches per block
#define BLK1 256

__device__ __forceinline__ void circuit_coeffs(const float* __restrict__ ry,
                                               float k[5]) {
    float U[4][4] = {{1,0,0,0},{0,1,0,0},{0,0,1,0},{0,0,0,1}};
    for (int l = 0; l < 2; ++l) {
        float c0 = cosf(0.5f * ry[l*4+0]), s0 = sinf(0.5f * ry[l*4+0]);
        float c1 = cosf(0.5f * ry[l*4+1]), s1 = sinf(0.5f * ry[l*4+1]);
        // RY on q0: rows (q1, 2+q1)
        for (int q1 = 0; q1 < 2; ++q1)
            for (int c = 0; c < 4; ++c) {
                float a = U[q1][c], d = U[2+q1][c];
                U[q1][c]   = c0*a - s0*d;
                U[2+q1][c] = s0*a + c0*d;
            }
        // RY on q1: rows (2m, 2m+1)
        for (int m = 0; m < 2; ++m)
            for (int c = 0; c < 4; ++c) {
                float a = U[2*m][c], d = U[2*m+1][c];
                U[2*m][c]   = c1*a - s1*d;
                U[2*m+1][c] = s1*a + c1*d;
            }
        // CNOT(0,1): swap rows 2,3
        for (int c = 0; c < 4; ++c) { float t = U[2][c]; U[2][c] = U[3][c]; U[3][c] = t; }
    }
    float pA=0, pB=0, pC=0, pD=0, pAD=0, pBC=0;
    for (int r = 0; r < 4; ++r) {
        float g = (r < 2) ? 1.f : -1.f;
        pA  += g * U[r][0] * U[r][0];
        pB  += g * U[r][1] * U[r][1];
        pC  += g * U[r][2] * U[r][2];
        pD  += g * U[r][3] * U[r][3];
        pAD += g * U[r][0] * U[r][3];
        pBC += g * U[r][1] * U[r][2];
    }
    k[0] = 0.25f * (pA + pB + pC + pD);
    k[1] = 0.25f * (pA + pB - pC - pD);
    k[2] = 0.25f * (pA - pB + pC - pD);
    k[3] = 0.25f * (pA - pB - pC + pD);
    k[4] = 0.50f * (pBC - pAD);
}

// Stage 1: per-(image, slice) partial sums -> ws[img*SLICES + slice].
// Every ws slot is written unconditionally, so no zero-init needed.
__global__ __launch_bounds__(BLK1) void partial_kernel(
    const float* __restrict__ x,
    const float* __restrict__ conv_w,
    const float* __restrict__ head_w,
    const float* __restrict__ ry,
    float* __restrict__ ws)
{
    __shared__ float sk[5];
    __shared__ float red[BLK1 / 64];
    const int tid   = threadIdx.x;
    const int slice = blockIdx.x;
    const int img   = blockIdx.y;

    if (tid == 0) {
        float k[5];
        circuit_coeffs(ry, k);
        for (int i = 0; i < 5; ++i) sk[i] = k[i];
    }
    __syncthreads();

    const float w0 = conv_w[0], w1 = conv_w[1], w2 = conv_w[2], w3 = conv_w[3];
    const float hw0 = head_w[0], hw1 = head_w[1];
    const float k1 = sk[1], k2 = sk[2], k3 = sk[3], k4 = sk[4];

    const float* __restrict__ xb = x + (size_t)img * XH * XW;
    const int p0 = slice * PPB;
    const int p1 = (p0 + PPB < NP) ? p0 + PPB : NP;

    float acc = 0.f;
    for (int p = p0 + tid; p < p1; p += BLK1) {
        int i = p / PW;           // magic-mul, cheap
        int j = p - i * PW;
        float x00 = xb[i * XW + j];
        float x01 = xb[i * XW + j + 1];
        float x10 = xb[(i + 1) * XW + j];
        float x11 = xb[(i + 1) * XW + j + 1];
        float conv = w0 * x00 + w1 * x01 + w2 * x10 + w3 * x11;
        float s0, c0, s1, c1;
        __sincosf(x00, &s0, &c0);
        __sincosf(x01, &s1, &c1);
        acc += hw0 * conv + hw1 * (k1 * c0 + k2 * c1 + k3 * c0 * c1 + k4 * s0 * s1);
    }

    for (int off = 32; off > 0; off >>= 1)
        acc += __shfl_down(acc, off, 64);
    if ((tid & 63) == 0) red[tid >> 6] = acc;
    __syncthreads();
    if (tid == 0) {
        float t = 0.f;
        for (int w = 0; w < BLK1 / 64; ++w) t += red[w];
        ws[img * SLICES + slice] = t;
    }
}

// Stage 2: one block of 64 threads; thread b finalizes image b.
__global__ __launch_bounds__(64) void final_kernel(
    const float* __restrict__ ws,
    const float* __restrict__ conv_b,
    const float* __restrict__ ry,
    const float* __restrict__ head_w,
    const float* __restrict__ head_b,
    float* __restrict__ out)
{
    const int b = threadIdx.x;
    float k[5];
    circuit_coeffs(ry, k);   // ~200 flops, redundant per thread — negligible
    float sum = 0.f;
    for (int s = 0; s < SLICES; ++s) sum += ws[b * SLICES + s];
    const float cconst = head_w[0] * conv_b[0] + head_w[1] * k[0] + head_b[0];
    out[b] = sum * (1.0f / NP) + cconst;
}

extern "C" void kernel_launch(void* const* d_in, const int* in_sizes, int n_in,
                              void* d_out, int out_size, void* d_ws, size_t ws_size,
                              hipStream_t stream) {
    const float* x      = (const float*)d_in[0];
    const float* conv_w = (const float*)d_in[1];
    const float* conv_b = (const float*)d_in[2];
    const float* ry     = (const float*)d_in[3];
    const float* head_w = (const float*)d_in[4];
    const float* head_b = (const float*)d_in[5];
    float* out = (float*)d_out;
    float* ws  = (float*)d_ws;    // NB*SLICES floats = 8 KB

    dim3 grid1(SLICES, NB);
    partial_kernel<<<grid1, BLK1, 0, stream>>>(x, conv_w, head_w, ry, ws);
    final_kernel<<<1, 64, 0, stream>>>(ws, conv_b, ry, head_w, head_b, out);
}